// Round 1
// baseline (72.323 us; speedup 1.0000x reference)
//
#include <hip/hip_runtime.h>

// CTC batch loss forward (Keras ctc_batch_cost semantics).
// B=2048, T=256, L=32, V=128, blank = V-1 = 127, S = 2L+1 = 65.
// One wave64 per batch item: lane s owns extended state s (0..63),
// lane 0 additionally owns state 64 (blank; shares lane 0's blank logp).

constexpr int Bb = 2048;
constexpr int Tt = 256;
constexpr int Ll = 32;
constexpr int Vv = 128;
constexpr int BLANK = Vv - 1;
#define EPSF 1e-7f
#define NEGF -1e30f

__global__ __launch_bounds__(256) void ctc_fwd(const int* __restrict__ y_true,
                                               const float* __restrict__ y_pred,
                                               float* __restrict__ out) {
    const int w    = blockIdx.x * 4 + (threadIdx.x >> 6);   // batch item
    const int lane = threadIdx.x & 63;

    // --- extended-label symbol for this lane's state ---
    int sym = BLANK;
    if (lane & 1) sym = y_true[w * Ll + (lane >> 1)];
    // skip transition allowed iff state is a label and differs from label 2 back
    const int sym2 = __shfl_up(sym, 2);
    const bool skip = (lane & 1) && (lane >= 3) && (sym != sym2);

    // per-lane column pointer into y_pred[b][t][sym]
    const float* rp = y_pred + ((size_t)w * Tt) * Vv + sym;

    // --- t = 0 init: only states 0 and 1 reachable ---
    const float lp0 = __logf(rp[0] + EPSF);
    float a   = (lane <= 1) ? lp0 : NEGF;   // alpha[lane]
    float a64 = NEGF;                       // alpha[64], meaningful on lane 0

    // --- one DP step given raw prob p = y_pred[b][t][sym] ---
    auto step = [&](float p) {
        const float lp  = __logf(p + EPSF);
        const float up1 = __shfl_up(a, 1);
        const float up2 = __shfl_up(a, 2);
        const float a63 = __uint_as_float(
            __builtin_amdgcn_readlane(__float_as_uint(a), 63));
        const float m1 = (lane >= 1) ? up1 : NEGF;
        const float m2 = skip ? up2 : NEGF;
        // 3-way logaddexp for states 0..63
        const float hi = fmaxf(a, fmaxf(m1, m2));
        const float sm = __expf(a - hi) + __expf(m1 - hi) + __expf(m2 - hi);
        const float na = hi + __logf(sm) + lp;
        // state 64 (blank): logaddexp(alpha[64], alpha[63]) + lp_blank
        // (lane 0's lp IS the blank logp; other lanes' a64 is dead)
        const float hi2 = fmaxf(a64, a63);
        const float sm2 = __expf(a64 - hi2) + __expf(a63 - hi2);
        a64 = hi2 + __logf(sm2) + lp;
        a   = na;
    };

    // --- software-pipelined main loop over t = 1..T-1 (255 steps) ---
    constexpr int PF = 8;                    // prefetch depth (static ring)
    float buf[PF];
#pragma unroll
    for (int i = 0; i < PF; ++i) buf[i] = rp[(size_t)(1 + i) * Vv];

    for (int tb = 1; tb + PF <= Tt; tb += PF) {   // tb = 1,9,...,241 -> t up to 248
#pragma unroll
        for (int i = 0; i < PF; ++i) {
            const float p  = buf[i];
            const int   tn = tb + i + PF;         // prefetch t+PF
            if (tn < Tt) buf[i] = rp[(size_t)tn * Vv];
            step(p);
        }
    }
    // tail: t = 249..255 (7 steps) already in buf[0..6]
#pragma unroll
    for (int i = 0; i < 7; ++i) step(buf[i]);

    // --- loss = -logaddexp(alpha[S-1]=a64, alpha[S-2]=alpha[63]) ---
    const float a63 = __uint_as_float(
        __builtin_amdgcn_readlane(__float_as_uint(a), 63));
    if (lane == 0) {
        const float hi = fmaxf(a64, a63);
        const float r  = hi + __logf(__expf(a64 - hi) + __expf(a63 - hi));
        out[w] = -r;
    }
}

extern "C" void kernel_launch(void* const* d_in, const int* in_sizes, int n_in,
                              void* d_out, int out_size, void* d_ws, size_t ws_size,
                              hipStream_t stream) {
    const int*   y_true = (const int*)d_in[0];
    const float* y_pred = (const float*)d_in[1];
    float*       out    = (float*)d_out;
    // 4 waves (4 batch items) per 256-thread block
    ctc_fwd<<<dim3(Bb / 4), dim3(256), 0, stream>>>(y_true, y_pred, out);
}